// Round 1
// baseline (696.061 us; speedup 1.0000x reference)
//
#include <hip/hip_runtime.h>
#include <hip/hip_bf16.h>

#define EPS 1e-8f

typedef short short8 __attribute__((ext_vector_type(8)));
typedef float f32x4 __attribute__((ext_vector_type(4)));

// ---- workspace layout (float offsets) ----
#define OF_FLAG   0L          // int flag: 0=f32 inputs, 1=bf16 inputs
#define OF_THETA  16L         // [B=4][66]
#define OF_SPH    4608L       // sp_h bf16 [n][m] (512x512 ushort = 512 KB)
#define OF_SPL    135680L     // sp_l bf16 residual [n][m]
#define OF_RSTB   266752L     // r'_odd buffer [64][32768]
#define OF_MI0    2363904L    // [i=0..10][slice][32768]  UNNORMALIZED v~_i, [t][n] per slice
#define OF_SCAL   25432576L   // nsq[k]@k*64 (k0..10); dotA[k]@704+k*64 (k0..9); dotB[k]@1344+(k-1)*64
#define OF_RSTA   25434624L   // r'_even buffer; becomes XST accumulator [t][n] after k1z zeroes it
#define OF_XST    25434624L

__device__ inline float ld_in(const void* p, long i, int bf) {
  if (bf) return __bfloat162float(((const __hip_bfloat16*)p)[i]);
  return ((const float*)p)[i];
}

// hi/lo bf16 split packed in u32: hi bits in low16, lo(residual) bits in high16
__device__ inline unsigned packw(float v) {
  unsigned u = __float_as_uint(v);
  unsigned h = u >> 16;
  float res = v - __uint_as_float(h << 16);
  return h | (__float_as_uint(res) & 0xFFFF0000u);
}
__device__ inline float recw(unsigned w) {
  return __uint_as_float(w << 16) + __uint_as_float(w & 0xFFFF0000u);
}

__device__ inline unsigned short bf16b(float v) {
  __hip_bfloat16 h = __float2bfloat16(v);
  return *(unsigned short*)&h;
}
__device__ inline float ubf(unsigned short u) {
  __hip_bfloat16 h = *(__hip_bfloat16*)&u;
  return __bfloat162float(h);
}
__device__ inline unsigned pk2(float a, float b) {
  return (unsigned)bf16b(a) | ((unsigned)bf16b(b) << 16);
}
__device__ inline float2 upk2(unsigned w) {
  return float2{ubf((unsigned short)(w & 0xFFFFu)), ubf((unsigned short)(w >> 16))};
}

// ---- block reductions (blockDim multiple of 64, <=1024) ----
__device__ inline void blk_reduce2(float& a, float& b, float* red) {
  #pragma unroll
  for (int off = 32; off > 0; off >>= 1) {
    a += __shfl_down(a, off, 64);
    b += __shfl_down(b, off, 64);
  }
  int w = threadIdx.x >> 6, lane = threadIdx.x & 63, nw = blockDim.x >> 6;
  __syncthreads();
  if (lane == 0) { red[w] = a; red[16 + w] = b; }
  __syncthreads();
  if (w == 0) {
    float sa = (lane < nw) ? red[lane] : 0.f;
    float sb = (lane < nw) ? red[16 + lane] : 0.f;
    #pragma unroll
    for (int off = 8; off > 0; off >>= 1) {
      sa += __shfl_down(sa, off, 64);
      sb += __shfl_down(sb, off, 64);
    }
    if (lane == 0) { red[32] = sa; red[33] = sb; }
  }
  __syncthreads();
  a = red[32]; b = red[33];
}

__device__ inline void blk_reduce1(float& a, float* red) {
  #pragma unroll
  for (int off = 32; off > 0; off >>= 1) a += __shfl_down(a, off, 64);
  int w = threadIdx.x >> 6, lane = threadIdx.x & 63, nw = blockDim.x >> 6;
  __syncthreads();
  if (lane == 0) red[w] = a;
  __syncthreads();
  if (w == 0) {
    float sa = (lane < nw) ? red[lane] : 0.f;
    #pragma unroll
    for (int off = 8; off > 0; off >>= 1) sa += __shfl_down(sa, off, 64);
    if (lane == 0) red[32] = sa;
  }
  __syncthreads();
  a = red[32];
}

// 3-value block reduction: one barrier round instead of two (k2m GS step).
__device__ inline void blk_reduce3(float& a, float& b, float& c, float* red) {
  #pragma unroll
  for (int off = 32; off > 0; off >>= 1) {
    a += __shfl_down(a, off, 64);
    b += __shfl_down(b, off, 64);
    c += __shfl_down(c, off, 64);
  }
  int w = threadIdx.x >> 6, lane = threadIdx.x & 63, nw = blockDim.x >> 6;
  __syncthreads();
  if (lane == 0) { red[w] = a; red[16 + w] = b; red[32 + w] = c; }
  __syncthreads();
  if (w == 0) {
    float sa = (lane < nw) ? red[lane] : 0.f;
    float sb = (lane < nw) ? red[16 + lane] : 0.f;
    float sc = (lane < nw) ? red[32 + lane] : 0.f;
    #pragma unroll
    for (int off = 8; off > 0; off >>= 1) {
      sa += __shfl_down(sa, off, 64);
      sb += __shfl_down(sb, off, 64);
      sc += __shfl_down(sc, off, 64);
    }
    if (lane == 0) { red[48] = sa; red[49] = sb; red[50] = sc; }
  }
  __syncthreads();
  a = red[48]; b = red[49]; c = red[50];
}

// ---- K0: dtype flag detect + theta MLP + zero scalar slots ----
__global__ void k0_theta(const void* ste, const void* w1, const void* b1,
                         const void* w2, const void* b2, const void* gamma,
                         float* ws) {
  __shared__ int sflag;
  int tid = threadIdx.x;
  if (tid == 0) {
    unsigned bits = ((const unsigned*)gamma)[0];   // bn_gamma[0] == 1.0
    int f = (bits == 0x3F800000u) ? 0 : 1;
    sflag = f;
    ((int*)ws)[OF_FLAG] = f;
  }
  __syncthreads();
  int bf = sflag;
  if (tid < 264) {
    int b = tid / 66, r = tid % 66, o = r / 11, p = r % 11;
    float acc = ld_in(b2, p, bf);
    for (int s = 0; s < 10; ++s) {
      float h1 = ld_in(b1, o, bf);
      for (int t = 0; t < 5; ++t)
        h1 += ld_in(w1, o * 5 + t, bf) * ld_in(ste, (long)(b * 5 + t) * 10 + s, bf);
      acc += ld_in(w2, p * 10 + s, bf) * h1;
    }
    ws[OF_THETA + b * 66 + r] = fmaxf(acc, 0.f);
  }
  for (int q = tid; q < 2048; q += blockDim.x) ws[OF_SCAL + q] = 0.f;
}

// ---- split sp into bf16 hi + residual-lo arrays [n][m] ----
__global__ void k_conv(const void* sp, float* ws) {
  int bf = ((const int*)ws)[0];
  long i = (long)blockIdx.x * blockDim.x + threadIdx.x;
  if (i < 262144L) {
    unsigned w = packw(ld_in(sp, i, bf));
    ((unsigned short*)(ws + OF_SPH))[i] = (unsigned short)(w & 0xFFFFu);
    ((unsigned short*)(ws + OF_SPL))[i] = (unsigned short)(w >> 16);
  }
}

// ---- per-slice nsq[0] = ||x||^2 (reads input directly) ----
__global__ __launch_bounds__(1024) void k_nrm0(const void* x, float* ws) {
  __shared__ float red[34];
  int slice = blockIdx.x, tid = threadIdx.x;
  int bf = ((const int*)ws)[0];
  long soff = (long)slice * 32768;
  float s = 0.f;
  #pragma unroll
  for (int k = 0; k < 32; ++k) { float v = ld_in(x, soff + k * 1024 + tid, bf); s += v * v; }
  blk_reduce1(s, red);
  if (tid == 0) ws[OF_SCAL + slice] = s;
}

// ---- v~_0 = x, stored TRANSPOSED [t][n] (unnormalized) ----
__global__ __launch_bounds__(256) void k_scaleT(const void* x, float* ws) {
  __shared__ float tile[64 * 65];
  int bid = blockIdx.x, tid = threadIdx.x;
  int slice = bid >> 3, nb = bid & 7;
  int bf = ((const int*)ws)[0];
  long soff = (long)slice * 32768;
  for (int q = 0; q < 16; ++q) {
    int idx = q * 256 + tid;
    int nl = idx >> 6, t = idx & 63;
    tile[nl * 65 + t] = ld_in(x, soff + (long)(nb * 64 + nl) * 64 + t, bf);
  }
  __syncthreads();
  float* mi = ws + OF_MI0 + soff;
  for (int q = 0; q < 16; ++q) {
    int idx = q * 256 + tid;
    int t = idx >> 6, nl = idx & 63;
    mi[t * 512 + nb * 64 + nl] = tile[nl * 65 + t];
  }
}

// ---- K1m (launch i=1..10): MFMA s-chain step.
//      Block = (slice, 16-t-row band tb). Phase A: compute v~_{i-1}[band][m]
//      from r'_{i-2}, v~_{i-2}, v~_{i-3} (unnormalized GS; scalars final since
//      last launch), write to global m1 + pack hi|lo into LDS W (A operand).
//      Phase B: r'_{i-1}[band][n] = v~ @ sp^T via 3-product bf16 MFMA split
//      (hh+hl+lh ~ fp32); B-frags are contiguous 16B loads from sp_h/sp_l
//      ([n][m] layout: one dwordx4 per frag, no unpack). Epilogue: dots.
__global__ __launch_bounds__(1024) void k1m(float* ws, int i) {
  __shared__ unsigned W[16 * 516];   // v~[t_local][m] packed hi|lo; stride 516 -> 2-way-only
  __shared__ float red[34];
  int tid = threadIdx.x, bid = blockIdx.x;
  int slice = bid >> 2, tb = bid & 3;
  long soff = (long)slice * 32768;
  float alpha = 0.f, beta = 0.f;
  if (i >= 2) alpha = ws[OF_SCAL + 704 + (i - 2) * 64 + slice] /
                      fmaxf(ws[OF_SCAL + (i - 2) * 64 + slice], 1e-30f);
  if (i >= 3) beta = ws[OF_SCAL + 1344 + (i - 3) * 64 + slice] /
                     fmaxf(ws[OF_SCAL + (i - 3) * 64 + slice], 1e-30f);
  const float* rp = ws + ((i & 1) ? OF_RSTB : OF_RSTA);        // r'_{i-2}
  float* m1 = ws + OF_MI0 + (long)(i - 1) * 2097152;
  const float* m2 = ws + OF_MI0 + (long)((i >= 2) ? i - 2 : 0) * 2097152;
  const float* m3 = ws + OF_MI0 + (long)((i >= 3) ? i - 3 : 0) * 2097152;

  // ---- Phase A: stage v~_{i-1} for this band ----
  float npp = 0.f;
  #pragma unroll
  for (int q = 0; q < 2; ++q) {
    int idx4 = q * 1024 + tid;
    int tl = idx4 >> 7, m4 = idx4 & 127;
    long off = soff + (long)(tb * 16 + tl) * 512 + m4 * 4;
    float4 v;
    if (i == 1) {
      v = *(const float4*)(ws + OF_MI0 + off);
    } else {
      float4 r = *(const float4*)(rp + off);
      float4 p1 = *(const float4*)(m2 + off);
      v.x = r.x - alpha * p1.x; v.y = r.y - alpha * p1.y;
      v.z = r.z - alpha * p1.z; v.w = r.w - alpha * p1.w;
      if (i >= 3) {
        float4 p2 = *(const float4*)(m3 + off);
        v.x -= beta * p2.x; v.y -= beta * p2.y;
        v.z -= beta * p2.z; v.w -= beta * p2.w;
      }
      *(float4*)(m1 + off) = v;
      npp += v.x * v.x + v.y * v.y + v.z * v.z + v.w * v.w;
    }
    unsigned* wp = &W[tl * 516 + m4 * 4];
    wp[0] = packw(v.x); wp[1] = packw(v.y); wp[2] = packw(v.z); wp[3] = packw(v.w);
  }
  if (i >= 2) {
    blk_reduce1(npp, red);
    if (tid == 0) atomicAdd(ws + OF_SCAL + (i - 1) * 64 + slice, npp);
  }
  __syncthreads();

  // ---- Phase B: MFMA r' = v~ @ sp^T for this band ----
  int w = tid >> 6, lane = tid & 63, quad = lane >> 4, col = lane & 15;
  const unsigned short* sph = (const unsigned short*)(ws + OF_SPH);
  const unsigned short* spl = (const unsigned short*)(ws + OF_SPL);
  int n0 = (w * 2) * 16 + col, n1 = (w * 2 + 1) * 16 + col;
  f32x4 C0 = {0.f, 0.f, 0.f, 0.f}, C1 = {0.f, 0.f, 0.f, 0.f};
  for (int kc = 0; kc < 16; ++kc) {
    int mbase = kc * 32 + quad * 8;
    const unsigned* ap = &W[col * 516 + mbase];
    unsigned wv0 = ap[0], wv1 = ap[1], wv2 = ap[2], wv3 = ap[3];
    unsigned wv4 = ap[4], wv5 = ap[5], wv6 = ap[6], wv7 = ap[7];
    short8 ah, al;
    ah[0] = (short)(wv0 & 0xFFFFu); al[0] = (short)(wv0 >> 16);
    ah[1] = (short)(wv1 & 0xFFFFu); al[1] = (short)(wv1 >> 16);
    ah[2] = (short)(wv2 & 0xFFFFu); al[2] = (short)(wv2 >> 16);
    ah[3] = (short)(wv3 & 0xFFFFu); al[3] = (short)(wv3 >> 16);
    ah[4] = (short)(wv4 & 0xFFFFu); al[4] = (short)(wv4 >> 16);
    ah[5] = (short)(wv5 & 0xFFFFu); al[5] = (short)(wv5 >> 16);
    ah[6] = (short)(wv6 & 0xFFFFu); al[6] = (short)(wv6 >> 16);
    ah[7] = (short)(wv7 & 0xFFFFu); al[7] = (short)(wv7 >> 16);
    short8 bh0 = *(const short8*)(sph + (long)n0 * 512 + mbase);
    short8 bl0 = *(const short8*)(spl + (long)n0 * 512 + mbase);
    short8 bh1 = *(const short8*)(sph + (long)n1 * 512 + mbase);
    short8 bl1 = *(const short8*)(spl + (long)n1 * 512 + mbase);
    C0 = __builtin_amdgcn_mfma_f32_16x16x32_bf16(ah, bh0, C0, 0, 0, 0);
    C0 = __builtin_amdgcn_mfma_f32_16x16x32_bf16(ah, bl0, C0, 0, 0, 0);
    C0 = __builtin_amdgcn_mfma_f32_16x16x32_bf16(al, bh0, C0, 0, 0, 0);
    C1 = __builtin_amdgcn_mfma_f32_16x16x32_bf16(ah, bh1, C1, 0, 0, 0);
    C1 = __builtin_amdgcn_mfma_f32_16x16x32_bf16(ah, bl1, C1, 0, 0, 0);
    C1 = __builtin_amdgcn_mfma_f32_16x16x32_bf16(al, bh1, C1, 0, 0, 0);
  }

  // ---- Epilogue: write r', accumulate dots ----
  float* ro = ws + (((i - 1) & 1) ? OF_RSTB : OF_RSTA);        // r'_{i-1}
  float d1p = 0.f, d2p = 0.f;
  #pragma unroll
  for (int r = 0; r < 4; ++r) {
    int tl = quad * 4 + r;
    long go = soff + (long)(tb * 16 + tl) * 512;
    float lv0 = recw(W[tl * 516 + n0]);
    float lv1 = recw(W[tl * 516 + n1]);
    d1p += C0[r] * lv0 + C1[r] * lv1;
    if (i >= 2) d2p += C0[r] * m2[go + n0] + C1[r] * m2[go + n1];
    ro[go + n0] = C0[r];
    ro[go + n1] = C1[r];
  }
  blk_reduce2(d1p, d2p, red);
  if (tid == 0) {
    atomicAdd(ws + OF_SCAL + 704 + (i - 1) * 64 + slice, d1p);
    if (i >= 2) atomicAdd(ws + OF_SCAL + 1344 + (i - 2) * 64 + slice, d2p);
  }
}

// ---- K1z: materialize v~_10, accumulate nsq[10], zero the XST accumulator ----
__global__ __launch_bounds__(1024) void k1z(float* ws) {
  __shared__ float red[34];
  long e = (long)blockIdx.x * 1024 + threadIdx.x;
  int slice = (int)(e >> 15);
  float alpha = ws[OF_SCAL + 704 + 9 * 64 + slice] / fmaxf(ws[OF_SCAL + 9 * 64 + slice], 1e-30f);
  float beta  = ws[OF_SCAL + 1344 + 8 * 64 + slice] / fmaxf(ws[OF_SCAL + 8 * 64 + slice], 1e-30f);
  float v = ws[OF_RSTB + e] - alpha * ws[OF_MI0 + 9L * 2097152 + e]
                            - beta  * ws[OF_MI0 + 8L * 2097152 + e];
  ws[OF_MI0 + 10L * 2097152 + e] = v;
  ws[OF_XST + e] = 0.f;
  float np = v * v;
  blk_reduce1(np, red);
  if (threadIdx.x == 0) atomicAdd(ws + OF_SCAL + 10 * 64 + slice, np);
}

// ---- K2m: bf16 MFMA t-chains.
//      Round-7 change: per GS step, fuse the dot pass and the norm pass.
//      Since d1p/d2p are computed against the SAME bf16 last/sec vectors that
//      get subtracted, ||C_new||^2 = ||C||^2 - d1p^2 - d2p^2 analytically
//      (error ~1e-5 relative, below bf16 chain noise). So: one blk_reduce3
//      (d1p,d2p,nrm) instead of blk_reduce2 + blk_reduce1, and 2 LDS passes
//      instead of 3. With 136KB LDS -> 1 block/CU, barrier latency is fully
//      exposed, so removing a reduction round pays directly.
__global__ __launch_bounds__(1024) void k2m(float* ws, const void* tp) {
  __shared__ unsigned LW[2][16384];
  __shared__ unsigned AH[2048];
  __shared__ float red[51];
  int tid = threadIdx.x;
  int slice = blockIdx.x / 11, ic = blockIdx.x % 11;
  int b = slice >> 4;
  int w = tid >> 6, lane = tid & 63, quad = lane >> 4, col = lane & 15;
  int mt = w & 3, ng = w >> 2;
  int bf = ((const int*)ws)[0];

  #pragma unroll
  for (int s = 0; s < 2; ++s) {
    int widx = s * 1024 + tid;
    int tq_ = widx & 3, ln = (widx >> 2) & 63, ktm = widx >> 8;
    int kt_ = ktm & 1, mt_ = ktm >> 1;
    int qd = ln >> 4, cl = ln & 15;
    int ua = mt_ * 16 + cl;
    int t0 = kt_ * 32 + qd * 8 + tq_ * 2;
    AH[widx] = pk2(ld_in(tp, (long)t0 * 64 + ua, bf),
                   ld_in(tp, (long)(t0 + 1) * 64 + ua, bf));
  }

  float rinv = 1.f / fmaxf(sqrtf(ws[OF_SCAL + ic * 64 + slice]), EPS);
  const float* seed = ws + OF_MI0 + (long)ic * 2097152 + (long)slice * 32768;

  for (int q = 0; q < 16; ++q) {
    int widx = q * 1024 + tid;
    int tpair = widx >> 9, n = widx & 511;
    float v0 = seed[(2 * tpair) * 512 + n] * rinv;
    float v1 = seed[(2 * tpair + 1) * 512 + n] * rinv;
    int li = ((tpair >> 2) * 512 + n) * 4 + (tpair & 3);
    LW[0][li] = pk2(v0, v1);
    LW[1][widx] = 0u;
  }
  __syncthreads();

  int t8c = mt * 2 + (quad >> 1);
  int tq0 = (quad * 2) & 3;
  float c0 = ws[OF_THETA + b * 66 + ic * 6 + 0];

  unsigned accP[16];
  #pragma unroll
  for (int nti = 0; nti < 8; ++nti) {
    int nn = ng * 128 + nti * 16 + col;
    int base = (t8c * 512 + nn) * 4;
    uint2 lw = *(uint2*)&LW[0][base + tq0];
    float2 p01 = upk2(lw.x), p23 = upk2(lw.y);
    accP[nti * 2] = pk2(c0 * p01.x, c0 * p01.y);
    accP[nti * 2 + 1] = pk2(c0 * p23.x, c0 * p23.y);
  }

  unsigned* cur = &LW[0][0];
  unsigned* prv = &LW[1][0];

  for (int j = 1; j <= 5; ++j) {
    f32x4 C[8];
    #pragma unroll
    for (int nti = 0; nti < 8; ++nti) C[nti] = (f32x4){0.f, 0.f, 0.f, 0.f};
    #pragma unroll
    for (int kt = 0; kt < 2; ++kt) {
      short8 a = *(short8*)&AH[((mt * 2 + kt) * 64 + lane) * 4];
      #pragma unroll
      for (int nti = 0; nti < 8; ++nti) {
        int bn = ng * 128 + nti * 16 + col;
        short8 bb = *(short8*)&cur[((kt * 4 + quad) * 512 + bn) * 4];
        C[nti] = __builtin_amdgcn_mfma_f32_16x16x32_bf16(a, bb, C[nti], 0, 0, 0);
      }
    }
    // Pass 1: dots AND raw norm in one sweep (nrm has no dependency on d1p/d2p)
    float d1p = 0.f, d2p = 0.f, nrm = 0.f;
    #pragma unroll
    for (int nti = 0; nti < 8; ++nti) {
      int nn = ng * 128 + nti * 16 + col;
      int base = (t8c * 512 + nn) * 4;
      uint2 lc = *(uint2*)&cur[base + tq0];
      uint2 lp = *(uint2*)&prv[base + tq0];
      float2 l01 = upk2(lc.x), l23 = upk2(lc.y);
      float2 s01 = upk2(lp.x), s23 = upk2(lp.y);
      d1p += C[nti][0] * l01.x + C[nti][1] * l01.y + C[nti][2] * l23.x + C[nti][3] * l23.y;
      d2p += C[nti][0] * s01.x + C[nti][1] * s01.y + C[nti][2] * s23.x + C[nti][3] * s23.y;
      nrm += C[nti][0] * C[nti][0] + C[nti][1] * C[nti][1]
           + C[nti][2] * C[nti][2] + C[nti][3] * C[nti][3];
    }
    blk_reduce3(d1p, d2p, nrm, red);
    // ||C - d1p*l - d2p*s||^2 = nrm - d1p^2 - d2p^2  (l,s orthonormal to ~1e-5)
    float np = fmaxf(nrm - d1p * d1p - d2p * d2p, 0.f);
    float ri = 1.f / fmaxf(sqrtf(np), EPS);
    float cj = ws[OF_THETA + b * 66 + ic * 6 + j];
    // Pass 2: update + normalize + theta-accumulate + write new basis
    #pragma unroll
    for (int nti = 0; nti < 8; ++nti) {
      int nn = ng * 128 + nti * 16 + col;
      int base = (t8c * 512 + nn) * 4;
      uint2 lc = *(uint2*)&cur[base + tq0];
      uint2 lp = *(uint2*)&prv[base + tq0];
      float2 l01 = upk2(lc.x), l23 = upk2(lc.y);
      float2 s01 = upk2(lp.x), s23 = upk2(lp.y);
      float vh0 = (C[nti][0] - d1p * l01.x - d2p * s01.x) * ri;
      float vh1 = (C[nti][1] - d1p * l01.y - d2p * s01.y) * ri;
      float vh2 = (C[nti][2] - d1p * l23.x - d2p * s23.x) * ri;
      float vh3 = (C[nti][3] - d1p * l23.y - d2p * s23.y) * ri;
      float2 a0 = upk2(accP[nti * 2]), a1 = upk2(accP[nti * 2 + 1]);
      accP[nti * 2] = pk2(a0.x + cj * vh0, a0.y + cj * vh1);
      accP[nti * 2 + 1] = pk2(a1.x + cj * vh2, a1.y + cj * vh3);
      uint2 nw; nw.x = pk2(vh0, vh1); nw.y = pk2(vh2, vh3);
      *(uint2*)&prv[base + tq0] = nw;
    }
    unsigned* t = cur; cur = prv; prv = t;
    __syncthreads();
  }
  float* xst = ws + OF_XST + (long)slice * 32768;
  // Stagger the atomic address stream by ic so the 11 chain-blocks of a
  // slice don't hit identical addresses in lockstep.
  #pragma unroll
  for (int k = 0; k < 8; ++k) {
    int nti = (k + ic) & 7;
    int nn = ng * 128 + nti * 16 + col;
    int u0 = mt * 16 + quad * 4;
    float2 a0 = upk2(accP[nti * 2]), a1 = upk2(accP[nti * 2 + 1]);
    atomicAdd(&xst[(u0 + 0) * 512 + nn], a0.x);
    atomicAdd(&xst[(u0 + 1) * 512 + nn], a0.y);
    atomicAdd(&xst[(u0 + 2) * 512 + nn], a1.x);
    atomicAdd(&xst[(u0 + 3) * 512 + nn], a1.y);
  }
}

// ---- K3: out = BN(MLP([x, x_st])); xst is [c][t][n] -> LDS tile transpose ----
__global__ __launch_bounds__(1024) void k3(const void* x, const void* wmlp, const void* bmlp,
    const void* gam, const void* bet, const void* mea, const void* var,
    const float* ws, void* out) {
  __shared__ float wA[64 * 16], wB[64 * 16], winv[64], wsh[64], wb[64];
  __shared__ float tile[16 * 64 * 17];   // [f][t][16n + pad]
  int tid = threadIdx.x, bid = blockIdx.x;
  int bf = ((const int*)ws)[0];
  int b = bid >> 5, nbase = (bid & 31) * 16;
  if (tid < 64) {
    float g = ld_in(gam, tid, bf), vv = ld_in(var, tid, bf);
    float iv = g / sqrtf(vv + 1e-5f);
    winv[tid] = iv;
    wsh[tid] = ld_in(bet, tid, bf) - ld_in(mea, tid, bf) * iv;
    wb[tid] = ld_in(bmlp, tid, bf);
  }
  for (int q = tid; q < 2048; q += 1024) {
    int o = q >> 5, c = q & 31;
    float v = ld_in(wmlp, q, bf);
    if (c < 16) wA[o * 16 + c] = v; else wB[o * 16 + (c - 16)] = v;
  }
  const float* xst = ws + OF_XST;
  #pragma unroll
  for (int q = 0; q < 4; ++q) {
    int idx = q * 1024 + tid;
    int f = idx >> 8, t = (idx >> 2) & 63, dn4 = idx & 3;
    float4 v = *(const float4*)(xst + ((long)(b * 16 + f)) * 32768 + t * 512 + nbase + dn4 * 4);
    float* dst = tile + f * 1088 + t * 17 + dn4 * 4;
    dst[0] = v.x; dst[1] = v.y; dst[2] = v.z; dst[3] = v.w;
  }
  __syncthreads();
  long pos = (long)(bid & 31) * 1024 + tid;
  int t = tid & 63, nl = tid >> 6;
  float xv[16], av[16];
  #pragma unroll
  for (int c = 0; c < 16; ++c)
    xv[c] = ld_in(x, ((long)(b * 16 + c)) * 32768 + pos, bf);
  #pragma unroll
  for (int f = 0; f < 16; ++f)
    av[f] = tile[f * 1088 + t * 17 + nl];
  #pragma unroll 4
  for (int o = 0; o < 64; ++o) {
    float s = wb[o];
    #pragma unroll
    for (int c = 0; c < 16; ++c) s += wA[o * 16 + c] * xv[c];
    #pragma unroll
    for (int f = 0; f < 16; ++f) s += wB[o * 16 + f] * av[f];
    s = s * winv[o] + wsh[o];
    long oi = ((long)(b * 64 + o)) * 32768 + pos;
    if (bf) ((__hip_bfloat16*)out)[oi] = __float2bfloat16(s);
    else ((float*)out)[oi] = s;
  }
}

extern "C" void kernel_launch(void* const* d_in, const int* in_sizes, int n_in,
                              void* d_out, int out_size, void* d_ws, size_t ws_size,
                              hipStream_t stream) {
  (void)in_sizes; (void)n_in; (void)out_size; (void)ws_size;
  float* ws = (float*)d_ws;

  k0_theta<<<1, 320, 0, stream>>>(d_in[3], d_in[4], d_in[5], d_in[6], d_in[7], d_in[10], ws);
  k_conv<<<256, 1024, 0, stream>>>(d_in[1], ws);
  k_nrm0<<<64, 1024, 0, stream>>>(d_in[0], ws);
  k_scaleT<<<512, 256, 0, stream>>>(d_in[0], ws);
  for (int i = 1; i <= 10; ++i)
    k1m<<<256, 1024, 0, stream>>>(ws, i);
  k1z<<<2048, 1024, 0, stream>>>(ws);
  k2m<<<704, 1024, 0, stream>>>(ws, d_in[2]);
  k3<<<128, 1024, 0, stream>>>(d_in[0], d_in[8], d_in[9], d_in[10], d_in[11], d_in[12], d_in[13],
                               ws, d_out);
}

// Round 2
// 655.638 us; speedup vs baseline: 1.0617x; 1.0617x over previous
//
#include <hip/hip_runtime.h>
#include <hip/hip_bf16.h>

#define EPS 1e-8f

typedef short short8 __attribute__((ext_vector_type(8)));
typedef float f32x4 __attribute__((ext_vector_type(4)));

// ---- workspace layout (float offsets) ----
#define OF_FLAG   0L          // int flag: 0=f32 inputs, 1=bf16 inputs
#define OF_THETA  16L         // [B=4][66]
#define OF_SPH    4608L       // sp_h bf16 [n][m] (512x512 ushort = 512 KB)
#define OF_SPL    135680L     // sp_l bf16 residual [n][m]
#define OF_RSTB   266752L     // r'_odd buffer [64][32768]
#define OF_MI0    2363904L    // [i=0..10][slice][32768]  UNNORMALIZED v~_i, [t][n] per slice
                              // (after k2m, region [ic][slice] holds that chain's XST partial)
#define OF_SCAL   25432576L   // nsq[k]@k*64 (k0..10); dotA[k]@704+k*64 (k0..9); dotB[k]@1344+(k-1)*64
#define OF_RSTA   25434624L   // r'_even buffer; becomes XST (written by k2r)
#define OF_XST    25434624L

__device__ inline float ld_in(const void* p, long i, int bf) {
  if (bf) return __bfloat162float(((const __hip_bfloat16*)p)[i]);
  return ((const float*)p)[i];
}

// hi/lo bf16 split packed in u32: hi bits in low16, lo(residual) bits in high16
__device__ inline unsigned packw(float v) {
  unsigned u = __float_as_uint(v);
  unsigned h = u >> 16;
  float res = v - __uint_as_float(h << 16);
  return h | (__float_as_uint(res) & 0xFFFF0000u);
}
__device__ inline float recw(unsigned w) {
  return __uint_as_float(w << 16) + __uint_as_float(w & 0xFFFF0000u);
}

__device__ inline unsigned short bf16b(float v) {
  __hip_bfloat16 h = __float2bfloat16(v);
  return *(unsigned short*)&h;
}
__device__ inline float ubf(unsigned short u) {
  __hip_bfloat16 h = *(__hip_bfloat16*)&u;
  return __bfloat162float(h);
}
__device__ inline unsigned pk2(float a, float b) {
  return (unsigned)bf16b(a) | ((unsigned)bf16b(b) << 16);
}
__device__ inline float2 upk2(unsigned w) {
  return float2{ubf((unsigned short)(w & 0xFFFFu)), ubf((unsigned short)(w >> 16))};
}

// ---- block reductions (blockDim multiple of 64, <=1024) ----
__device__ inline void blk_reduce2(float& a, float& b, float* red) {
  #pragma unroll
  for (int off = 32; off > 0; off >>= 1) {
    a += __shfl_down(a, off, 64);
    b += __shfl_down(b, off, 64);
  }
  int w = threadIdx.x >> 6, lane = threadIdx.x & 63, nw = blockDim.x >> 6;
  __syncthreads();
  if (lane == 0) { red[w] = a; red[16 + w] = b; }
  __syncthreads();
  if (w == 0) {
    float sa = (lane < nw) ? red[lane] : 0.f;
    float sb = (lane < nw) ? red[16 + lane] : 0.f;
    #pragma unroll
    for (int off = 8; off > 0; off >>= 1) {
      sa += __shfl_down(sa, off, 64);
      sb += __shfl_down(sb, off, 64);
    }
    if (lane == 0) { red[32] = sa; red[33] = sb; }
  }
  __syncthreads();
  a = red[32]; b = red[33];
}

__device__ inline void blk_reduce1(float& a, float* red) {
  #pragma unroll
  for (int off = 32; off > 0; off >>= 1) a += __shfl_down(a, off, 64);
  int w = threadIdx.x >> 6, lane = threadIdx.x & 63, nw = blockDim.x >> 6;
  __syncthreads();
  if (lane == 0) red[w] = a;
  __syncthreads();
  if (w == 0) {
    float sa = (lane < nw) ? red[lane] : 0.f;
    #pragma unroll
    for (int off = 8; off > 0; off >>= 1) sa += __shfl_down(sa, off, 64);
    if (lane == 0) red[32] = sa;
  }
  __syncthreads();
  a = red[32];
}

// ---- K0: dtype flag detect + theta MLP + zero scalar slots ----
__global__ void k0_theta(const void* ste, const void* w1, const void* b1,
                         const void* w2, const void* b2, const void* gamma,
                         float* ws) {
  __shared__ int sflag;
  int tid = threadIdx.x;
  if (tid == 0) {
    unsigned bits = ((const unsigned*)gamma)[0];   // bn_gamma[0] == 1.0
    int f = (bits == 0x3F800000u) ? 0 : 1;
    sflag = f;
    ((int*)ws)[OF_FLAG] = f;
  }
  __syncthreads();
  int bf = sflag;
  if (tid < 264) {
    int b = tid / 66, r = tid % 66, o = r / 11, p = r % 11;
    float acc = ld_in(b2, p, bf);
    for (int s = 0; s < 10; ++s) {
      float h1 = ld_in(b1, o, bf);
      for (int t = 0; t < 5; ++t)
        h1 += ld_in(w1, o * 5 + t, bf) * ld_in(ste, (long)(b * 5 + t) * 10 + s, bf);
      acc += ld_in(w2, p * 10 + s, bf) * h1;
    }
    ws[OF_THETA + b * 66 + r] = fmaxf(acc, 0.f);
  }
  for (int q = tid; q < 2048; q += blockDim.x) ws[OF_SCAL + q] = 0.f;
}

// ---- split sp into bf16 hi + residual-lo arrays [n][m] ----
__global__ void k_conv(const void* sp, float* ws) {
  int bf = ((const int*)ws)[0];
  long i = (long)blockIdx.x * blockDim.x + threadIdx.x;
  if (i < 262144L) {
    unsigned w = packw(ld_in(sp, i, bf));
    ((unsigned short*)(ws + OF_SPH))[i] = (unsigned short)(w & 0xFFFFu);
    ((unsigned short*)(ws + OF_SPL))[i] = (unsigned short)(w >> 16);
  }
}

// ---- per-slice nsq[0] = ||x||^2 (reads input directly) ----
__global__ __launch_bounds__(1024) void k_nrm0(const void* x, float* ws) {
  __shared__ float red[34];
  int slice = blockIdx.x, tid = threadIdx.x;
  int bf = ((const int*)ws)[0];
  long soff = (long)slice * 32768;
  float s = 0.f;
  #pragma unroll
  for (int k = 0; k < 32; ++k) { float v = ld_in(x, soff + k * 1024 + tid, bf); s += v * v; }
  blk_reduce1(s, red);
  if (tid == 0) ws[OF_SCAL + slice] = s;
}

// ---- v~_0 = x, stored TRANSPOSED [t][n] (unnormalized) ----
__global__ __launch_bounds__(256) void k_scaleT(const void* x, float* ws) {
  __shared__ float tile[64 * 65];
  int bid = blockIdx.x, tid = threadIdx.x;
  int slice = bid >> 3, nb = bid & 7;
  int bf = ((const int*)ws)[0];
  long soff = (long)slice * 32768;
  for (int q = 0; q < 16; ++q) {
    int idx = q * 256 + tid;
    int nl = idx >> 6, t = idx & 63;
    tile[nl * 65 + t] = ld_in(x, soff + (long)(nb * 64 + nl) * 64 + t, bf);
  }
  __syncthreads();
  float* mi = ws + OF_MI0 + soff;
  for (int q = 0; q < 16; ++q) {
    int idx = q * 256 + tid;
    int t = idx >> 6, nl = idx & 63;
    mi[t * 512 + nb * 64 + nl] = tile[nl * 65 + t];
  }
}

// ---- K1m (launch i=1..10): MFMA s-chain step.
//      __launch_bounds__(1024,4): LDS/grid pin 1 block/CU anyway, so allow up
//      to 128 VGPRs -> compiler can keep more B-frag loads in flight.
__global__ __launch_bounds__(1024, 4) void k1m(float* ws, int i) {
  __shared__ unsigned W[16 * 516];   // v~[t_local][m] packed hi|lo; stride 516 -> 2-way-only
  __shared__ float red[34];
  int tid = threadIdx.x, bid = blockIdx.x;
  int slice = bid >> 2, tb = bid & 3;
  long soff = (long)slice * 32768;
  float alpha = 0.f, beta = 0.f;
  if (i >= 2) alpha = ws[OF_SCAL + 704 + (i - 2) * 64 + slice] /
                      fmaxf(ws[OF_SCAL + (i - 2) * 64 + slice], 1e-30f);
  if (i >= 3) beta = ws[OF_SCAL + 1344 + (i - 3) * 64 + slice] /
                     fmaxf(ws[OF_SCAL + (i - 3) * 64 + slice], 1e-30f);
  const float* rp = ws + ((i & 1) ? OF_RSTB : OF_RSTA);        // r'_{i-2}
  float* m1 = ws + OF_MI0 + (long)(i - 1) * 2097152;
  const float* m2 = ws + OF_MI0 + (long)((i >= 2) ? i - 2 : 0) * 2097152;
  const float* m3 = ws + OF_MI0 + (long)((i >= 3) ? i - 3 : 0) * 2097152;

  // ---- Phase A: stage v~_{i-1} for this band ----
  float npp = 0.f;
  #pragma unroll
  for (int q = 0; q < 2; ++q) {
    int idx4 = q * 1024 + tid;
    int tl = idx4 >> 7, m4 = idx4 & 127;
    long off = soff + (long)(tb * 16 + tl) * 512 + m4 * 4;
    float4 v;
    if (i == 1) {
      v = *(const float4*)(ws + OF_MI0 + off);
    } else {
      float4 r = *(const float4*)(rp + off);
      float4 p1 = *(const float4*)(m2 + off);
      v.x = r.x - alpha * p1.x; v.y = r.y - alpha * p1.y;
      v.z = r.z - alpha * p1.z; v.w = r.w - alpha * p1.w;
      if (i >= 3) {
        float4 p2 = *(const float4*)(m3 + off);
        v.x -= beta * p2.x; v.y -= beta * p2.y;
        v.z -= beta * p2.z; v.w -= beta * p2.w;
      }
      *(float4*)(m1 + off) = v;
      npp += v.x * v.x + v.y * v.y + v.z * v.z + v.w * v.w;
    }
    unsigned* wp = &W[tl * 516 + m4 * 4];
    wp[0] = packw(v.x); wp[1] = packw(v.y); wp[2] = packw(v.z); wp[3] = packw(v.w);
  }
  if (i >= 2) {
    blk_reduce1(npp, red);
    if (tid == 0) atomicAdd(ws + OF_SCAL + (i - 1) * 64 + slice, npp);
  }
  __syncthreads();

  // ---- Phase B: MFMA r' = v~ @ sp^T for this band ----
  int w = tid >> 6, lane = tid & 63, quad = lane >> 4, col = lane & 15;
  const unsigned short* sph = (const unsigned short*)(ws + OF_SPH);
  const unsigned short* spl = (const unsigned short*)(ws + OF_SPL);
  int n0 = (w * 2) * 16 + col, n1 = (w * 2 + 1) * 16 + col;
  f32x4 C0 = {0.f, 0.f, 0.f, 0.f}, C1 = {0.f, 0.f, 0.f, 0.f};
  for (int kc = 0; kc < 16; ++kc) {
    int mbase = kc * 32 + quad * 8;
    const unsigned* ap = &W[col * 516 + mbase];
    unsigned wv0 = ap[0], wv1 = ap[1], wv2 = ap[2], wv3 = ap[3];
    unsigned wv4 = ap[4], wv5 = ap[5], wv6 = ap[6], wv7 = ap[7];
    short8 ah, al;
    ah[0] = (short)(wv0 & 0xFFFFu); al[0] = (short)(wv0 >> 16);
    ah[1] = (short)(wv1 & 0xFFFFu); al[1] = (short)(wv1 >> 16);
    ah[2] = (short)(wv2 & 0xFFFFu); al[2] = (short)(wv2 >> 16);
    ah[3] = (short)(wv3 & 0xFFFFu); al[3] = (short)(wv3 >> 16);
    ah[4] = (short)(wv4 & 0xFFFFu); al[4] = (short)(wv4 >> 16);
    ah[5] = (short)(wv5 & 0xFFFFu); al[5] = (short)(wv5 >> 16);
    ah[6] = (short)(wv6 & 0xFFFFu); al[6] = (short)(wv6 >> 16);
    ah[7] = (short)(wv7 & 0xFFFFu); al[7] = (short)(wv7 >> 16);
    short8 bh0 = *(const short8*)(sph + (long)n0 * 512 + mbase);
    short8 bl0 = *(const short8*)(spl + (long)n0 * 512 + mbase);
    short8 bh1 = *(const short8*)(sph + (long)n1 * 512 + mbase);
    short8 bl1 = *(const short8*)(spl + (long)n1 * 512 + mbase);
    C0 = __builtin_amdgcn_mfma_f32_16x16x32_bf16(ah, bh0, C0, 0, 0, 0);
    C0 = __builtin_amdgcn_mfma_f32_16x16x32_bf16(ah, bl0, C0, 0, 0, 0);
    C0 = __builtin_amdgcn_mfma_f32_16x16x32_bf16(al, bh0, C0, 0, 0, 0);
    C1 = __builtin_amdgcn_mfma_f32_16x16x32_bf16(ah, bh1, C1, 0, 0, 0);
    C1 = __builtin_amdgcn_mfma_f32_16x16x32_bf16(ah, bl1, C1, 0, 0, 0);
    C1 = __builtin_amdgcn_mfma_f32_16x16x32_bf16(al, bh1, C1, 0, 0, 0);
  }

  // ---- Epilogue: write r', accumulate dots ----
  float* ro = ws + (((i - 1) & 1) ? OF_RSTB : OF_RSTA);        // r'_{i-1}
  float d1p = 0.f, d2p = 0.f;
  #pragma unroll
  for (int r = 0; r < 4; ++r) {
    int tl = quad * 4 + r;
    long go = soff + (long)(tb * 16 + tl) * 512;
    float lv0 = recw(W[tl * 516 + n0]);
    float lv1 = recw(W[tl * 516 + n1]);
    d1p += C0[r] * lv0 + C1[r] * lv1;
    if (i >= 2) d2p += C0[r] * m2[go + n0] + C1[r] * m2[go + n1];
    ro[go + n0] = C0[r];
    ro[go + n1] = C1[r];
  }
  blk_reduce2(d1p, d2p, red);
  if (tid == 0) {
    atomicAdd(ws + OF_SCAL + 704 + (i - 1) * 64 + slice, d1p);
    if (i >= 2) atomicAdd(ws + OF_SCAL + 1344 + (i - 2) * 64 + slice, d2p);
  }
}

// ---- K1z: materialize v~_10, accumulate nsq[10] (XST now written by k2r) ----
__global__ __launch_bounds__(1024) void k1z(float* ws) {
  __shared__ float red[34];
  long e = (long)blockIdx.x * 1024 + threadIdx.x;
  int slice = (int)(e >> 15);
  float alpha = ws[OF_SCAL + 704 + 9 * 64 + slice] / fmaxf(ws[OF_SCAL + 9 * 64 + slice], 1e-30f);
  float beta  = ws[OF_SCAL + 1344 + 8 * 64 + slice] / fmaxf(ws[OF_SCAL + 8 * 64 + slice], 1e-30f);
  float v = ws[OF_RSTB + e] - alpha * ws[OF_MI0 + 9L * 2097152 + e]
                            - beta  * ws[OF_MI0 + 8L * 2097152 + e];
  ws[OF_MI0 + 10L * 2097152 + e] = v;
  float np = v * v;
  blk_reduce1(np, red);
  if (threadIdx.x == 0) atomicAdd(ws + OF_SCAL + 10 * 64 + slice, np);
}

// ---- K2m: bf16 MFMA t-chains.
//      Round-8 changes (theory: fixed per-block costs dominate, not per-step math):
//      (1) epilogue atomics (23M device atomicAdds, 204MB HBM writes) -> plain
//          f32 partial stores into this block's own consumed seed region
//          MI0[ic][slice]; k2r sums the 11 partials afterward.
//      (2) GS-step reduction: per-wave shuffle + LDS atomicAdd into per-step
//          slots + ONE barrier (was a 3-barrier two-stage dance). 2 barriers
//          per step total.
//      (3) launch_bounds(1024,4): 1 block/CU is LDS-pinned anyway, so allow
//          128 VGPRs; stash pass-1 LDS reads in registers across the barrier
//          so pass 2 does no LDS reads.
__global__ __launch_bounds__(1024, 4) void k2m(float* ws, const void* tp) {
  __shared__ unsigned LW[2][16384];
  __shared__ unsigned AH[2048];
  __shared__ float red[24];          // [j=1..5][d1,d2,nrm,pad]
  int tid = threadIdx.x;
  int slice = blockIdx.x / 11, ic = blockIdx.x % 11;
  int b = slice >> 4;
  int w = tid >> 6, lane = tid & 63, quad = lane >> 4, col = lane & 15;
  int mt = w & 3, ng = w >> 2;
  int bf = ((const int*)ws)[0];

  #pragma unroll
  for (int s = 0; s < 2; ++s) {
    int widx = s * 1024 + tid;
    int tq_ = widx & 3, ln = (widx >> 2) & 63, ktm = widx >> 8;
    int kt_ = ktm & 1, mt_ = ktm >> 1;
    int qd = ln >> 4, cl = ln & 15;
    int ua = mt_ * 16 + cl;
    int t0 = kt_ * 32 + qd * 8 + tq_ * 2;
    AH[widx] = pk2(ld_in(tp, (long)t0 * 64 + ua, bf),
                   ld_in(tp, (long)(t0 + 1) * 64 + ua, bf));
  }
  if (tid < 24) red[tid] = 0.f;

  float rinv = 1.f / fmaxf(sqrtf(ws[OF_SCAL + ic * 64 + slice]), EPS);
  float* seed = ws + OF_MI0 + (long)ic * 2097152 + (long)slice * 32768;

  for (int q = 0; q < 16; ++q) {
    int widx = q * 1024 + tid;
    int tpair = widx >> 9, n = widx & 511;
    float v0 = seed[(2 * tpair) * 512 + n] * rinv;
    float v1 = seed[(2 * tpair + 1) * 512 + n] * rinv;
    int li = ((tpair >> 2) * 512 + n) * 4 + (tpair & 3);
    LW[0][li] = pk2(v0, v1);
    LW[1][widx] = 0u;
  }
  __syncthreads();

  int t8c = mt * 2 + (quad >> 1);
  int tq0 = (quad * 2) & 3;
  float c0 = ws[OF_THETA + b * 66 + ic * 6 + 0];

  unsigned accP[16];
  #pragma unroll
  for (int nti = 0; nti < 8; ++nti) {
    int nn = ng * 128 + nti * 16 + col;
    int base = (t8c * 512 + nn) * 4;
    uint2 lw = *(uint2*)&LW[0][base + tq0];
    float2 p01 = upk2(lw.x), p23 = upk2(lw.y);
    accP[nti * 2] = pk2(c0 * p01.x, c0 * p01.y);
    accP[nti * 2 + 1] = pk2(c0 * p23.x, c0 * p23.y);
  }

  unsigned* cur = &LW[0][0];
  unsigned* prv = &LW[1][0];

  for (int j = 1; j <= 5; ++j) {
    f32x4 C[8];
    #pragma unroll
    for (int nti = 0; nti < 8; ++nti) C[nti] = (f32x4){0.f, 0.f, 0.f, 0.f};
    #pragma unroll
    for (int kt = 0; kt < 2; ++kt) {
      short8 a = *(short8*)&AH[((mt * 2 + kt) * 64 + lane) * 4];
      #pragma unroll
      for (int nti = 0; nti < 8; ++nti) {
        int bn = ng * 128 + nti * 16 + col;
        short8 bb = *(short8*)&cur[((kt * 4 + quad) * 512 + bn) * 4];
        C[nti] = __builtin_amdgcn_mfma_f32_16x16x32_bf16(a, bb, C[nti], 0, 0, 0);
      }
    }
    // Pass 1: dots + raw norm; stash LDS reads in regs for pass 2.
    uint2 rlc[8], rlp[8];
    float d1p = 0.f, d2p = 0.f, nrm = 0.f;
    #pragma unroll
    for (int nti = 0; nti < 8; ++nti) {
      int nn = ng * 128 + nti * 16 + col;
      int base = (t8c * 512 + nn) * 4;
      rlc[nti] = *(uint2*)&cur[base + tq0];
      rlp[nti] = *(uint2*)&prv[base + tq0];
      float2 l01 = upk2(rlc[nti].x), l23 = upk2(rlc[nti].y);
      float2 s01 = upk2(rlp[nti].x), s23 = upk2(rlp[nti].y);
      d1p += C[nti][0] * l01.x + C[nti][1] * l01.y + C[nti][2] * l23.x + C[nti][3] * l23.y;
      d2p += C[nti][0] * s01.x + C[nti][1] * s01.y + C[nti][2] * s23.x + C[nti][3] * s23.y;
      nrm += C[nti][0] * C[nti][0] + C[nti][1] * C[nti][1]
           + C[nti][2] * C[nti][2] + C[nti][3] * C[nti][3];
    }
    // One-barrier block reduce: wave shuffle + LDS atomics into step slots.
    #pragma unroll
    for (int off = 32; off > 0; off >>= 1) {
      d1p += __shfl_down(d1p, off, 64);
      d2p += __shfl_down(d2p, off, 64);
      nrm += __shfl_down(nrm, off, 64);
    }
    if (lane == 0) {
      atomicAdd(&red[j * 4 + 0], d1p);
      atomicAdd(&red[j * 4 + 1], d2p);
      atomicAdd(&red[j * 4 + 2], nrm);
    }
    __syncthreads();       // also orders MFMA B-reads before pass-2 writes
    float d1 = red[j * 4 + 0], d2 = red[j * 4 + 1], nr = red[j * 4 + 2];
    // ||C - d1*l - d2*s||^2 = nr - d1^2 - d2^2  (l,s orthonormal to ~1e-5)
    float np = fmaxf(nr - d1 * d1 - d2 * d2, 0.f);
    float ri = 1.f / fmaxf(sqrtf(np), EPS);
    float cj = ws[OF_THETA + b * 66 + ic * 6 + j];
    // Pass 2: update + normalize + theta-accumulate + write new basis (regs only + LDS writes)
    #pragma unroll
    for (int nti = 0; nti < 8; ++nti) {
      int nn = ng * 128 + nti * 16 + col;
      int base = (t8c * 512 + nn) * 4;
      float2 l01 = upk2(rlc[nti].x), l23 = upk2(rlc[nti].y);
      float2 s01 = upk2(rlp[nti].x), s23 = upk2(rlp[nti].y);
      float vh0 = (C[nti][0] - d1 * l01.x - d2 * s01.x) * ri;
      float vh1 = (C[nti][1] - d1 * l01.y - d2 * s01.y) * ri;
      float vh2 = (C[nti][2] - d1 * l23.x - d2 * s23.x) * ri;
      float vh3 = (C[nti][3] - d1 * l23.y - d2 * s23.y) * ri;
      float2 a0 = upk2(accP[nti * 2]), a1 = upk2(accP[nti * 2 + 1]);
      accP[nti * 2] = pk2(a0.x + cj * vh0, a0.y + cj * vh1);
      accP[nti * 2 + 1] = pk2(a1.x + cj * vh2, a1.y + cj * vh3);
      uint2 nw; nw.x = pk2(vh0, vh1); nw.y = pk2(vh2, vh3);
      *(uint2*)&prv[base + tq0] = nw;
    }
    unsigned* t = cur; cur = prv; prv = t;
    __syncthreads();
  }
  // Plain f32 partial store into this block's own seed region (sole owner).
  float* po = seed;
  #pragma unroll
  for (int nti = 0; nti < 8; ++nti) {
    int nn = ng * 128 + nti * 16 + col;
    int u0 = mt * 16 + quad * 4;
    float2 a0 = upk2(accP[nti * 2]), a1 = upk2(accP[nti * 2 + 1]);
    po[(u0 + 0) * 512 + nn] = a0.x;
    po[(u0 + 1) * 512 + nn] = a0.y;
    po[(u0 + 2) * 512 + nn] = a1.x;
    po[(u0 + 3) * 512 + nn] = a1.y;
  }
}

// ---- K2r: XST = sum over ic of the 11 chain partials (streaming, no atomics) ----
__global__ __launch_bounds__(256) void k2r(float* ws) {
  long i = ((long)blockIdx.x * 256 + threadIdx.x) * 4;
  float4 s = *(const float4*)(ws + OF_MI0 + i);
  #pragma unroll
  for (int ic = 1; ic <= 10; ++ic) {
    float4 v = *(const float4*)(ws + OF_MI0 + (long)ic * 2097152 + i);
    s.x += v.x; s.y += v.y; s.z += v.z; s.w += v.w;
  }
  *(float4*)(ws + OF_XST + i) = s;
}

// ---- K3: out = BN(MLP([x, x_st])); xst is [c][t][n] -> LDS tile transpose ----
__global__ __launch_bounds__(1024) void k3(const void* x, const void* wmlp, const void* bmlp,
    const void* gam, const void* bet, const void* mea, const void* var,
    const float* ws, void* out) {
  __shared__ float wA[64 * 16], wB[64 * 16], winv[64], wsh[64], wb[64];
  __shared__ float tile[16 * 64 * 17];   // [f][t][16n + pad]
  int tid = threadIdx.x, bid = blockIdx.x;
  int bf = ((const int*)ws)[0];
  int b = bid >> 5, nbase = (bid & 31) * 16;
  if (tid < 64) {
    float g = ld_in(gam, tid, bf), vv = ld_in(var, tid, bf);
    float iv = g / sqrtf(vv + 1e-5f);
    winv[tid] = iv;
    wsh[tid] = ld_in(bet, tid, bf) - ld_in(mea, tid, bf) * iv;
    wb[tid] = ld_in(bmlp, tid, bf);
  }
  for (int q = tid; q < 2048; q += 1024) {
    int o = q >> 5, c = q & 31;
    float v = ld_in(wmlp, q, bf);
    if (c < 16) wA[o * 16 + c] = v; else wB[o * 16 + (c - 16)] = v;
  }
  const float* xst = ws + OF_XST;
  #pragma unroll
  for (int q = 0; q < 4; ++q) {
    int idx = q * 1024 + tid;
    int f = idx >> 8, t = (idx >> 2) & 63, dn4 = idx & 3;
    float4 v = *(const float4*)(xst + ((long)(b * 16 + f)) * 32768 + t * 512 + nbase + dn4 * 4);
    float* dst = tile + f * 1088 + t * 17 + dn4 * 4;
    dst[0] = v.x; dst[1] = v.y; dst[2] = v.z; dst[3] = v.w;
  }
  __syncthreads();
  long pos = (long)(bid & 31) * 1024 + tid;
  int t = tid & 63, nl = tid >> 6;
  float xv[16], av[16];
  #pragma unroll
  for (int c = 0; c < 16; ++c)
    xv[c] = ld_in(x, ((long)(b * 16 + c)) * 32768 + pos, bf);
  #pragma unroll
  for (int f = 0; f < 16; ++f)
    av[f] = tile[f * 1088 + t * 17 + nl];
  #pragma unroll 4
  for (int o = 0; o < 64; ++o) {
    float s = wb[o];
    #pragma unroll
    for (int c = 0; c < 16; ++c) s += wA[o * 16 + c] * xv[c];
    #pragma unroll
    for (int f = 0; f < 16; ++f) s += wB[o * 16 + f] * av[f];
    s = s * winv[o] + wsh[o];
    long oi = ((long)(b * 64 + o)) * 32768 + pos;
    if (bf) ((__hip_bfloat16*)out)[oi] = __float2bfloat16(s);
    else ((float*)out)[oi] = s;
  }
}

extern "C" void kernel_launch(void* const* d_in, const int* in_sizes, int n_in,
                              void* d_out, int out_size, void* d_ws, size_t ws_size,
                              hipStream_t stream) {
  (void)in_sizes; (void)n_in; (void)out_size; (void)ws_size;
  float* ws = (float*)d_ws;

  k0_theta<<<1, 320, 0, stream>>>(d_in[3], d_in[4], d_in[5], d_in[6], d_in[7], d_in[10], ws);
  k_conv<<<256, 1024, 0, stream>>>(d_in[1], ws);
  k_nrm0<<<64, 1024, 0, stream>>>(d_in[0], ws);
  k_scaleT<<<512, 256, 0, stream>>>(d_in[0], ws);
  for (int i = 1; i <= 10; ++i)
    k1m<<<256, 1024, 0, stream>>>(ws, i);
  k1z<<<2048, 1024, 0, stream>>>(ws);
  k2m<<<704, 1024, 0, stream>>>(ws, d_in[2]);
  k2r<<<2048, 256, 0, stream>>>(ws);
  k3<<<128, 1024, 0, stream>>>(d_in[0], d_in[8], d_in[9], d_in[10], d_in[11], d_in[12], d_in[13],
                               ws, d_out);
}

// Round 3
// 443.978 us; speedup vs baseline: 1.5678x; 1.4767x over previous
//
#include <hip/hip_runtime.h>
#include <hip/hip_bf16.h>

#define EPS 1e-8f

typedef short short8 __attribute__((ext_vector_type(8)));
typedef float f32x4 __attribute__((ext_vector_type(4)));
typedef unsigned short u16x4 __attribute__((ext_vector_type(4)));

// ---- workspace layout (float offsets) ----
#define OF_FLAG   0L          // int flag: 0=f32 inputs, 1=bf16 inputs
#define OF_THETA  16L         // [B=4][66]
#define OF_SPH    4608L       // sp_h bf16, FRAGMENT-MAJOR: [(ng2*16+kc)*64 + quad*16+col]*8+e
#define OF_SPL    135680L     // sp_l bf16 residual, same layout
#define OF_BAR    266752L     // slice barrier counters (int), reusing dead RSTB area
#define OF_MI0    2363904L    // [i=0..10][slice][32768]  UNNORMALIZED v~_i, [t][n] per slice
                              // (after k2m, region [ic][slice] holds that chain's XST partial)
#define OF_SCAL   25432576L   // nsq[k]@k*64 (k0..10); dotA[k]@704+k*64 (k0..9); dotB[k]@1344+(k-1)*64
#define OF_XST    25434624L   // XST accumulator (written by k2r)

__device__ inline float ld_in(const void* p, long i, int bf) {
  if (bf) return __bfloat162float(((const __hip_bfloat16*)p)[i]);
  return ((const float*)p)[i];
}

// hi/lo bf16 split packed in u32: hi bits in low16, lo(residual) bits in high16
__device__ inline unsigned packw(float v) {
  unsigned u = __float_as_uint(v);
  unsigned h = u >> 16;
  float res = v - __uint_as_float(h << 16);
  return h | (__float_as_uint(res) & 0xFFFF0000u);
}

__device__ inline unsigned short bf16b(float v) {
  __hip_bfloat16 h = __float2bfloat16(v);
  return *(unsigned short*)&h;
}
__device__ inline float ubf(unsigned short u) {
  __hip_bfloat16 h = *(__hip_bfloat16*)&u;
  return __bfloat162float(h);
}
__device__ inline unsigned pk2(float a, float b) {
  return (unsigned)bf16b(a) | ((unsigned)bf16b(b) << 16);
}
__device__ inline float2 upk2(unsigned w) {
  return float2{ubf((unsigned short)(w & 0xFFFFu)), ubf((unsigned short)(w >> 16))};
}

// ---- block reductions (blockDim multiple of 64, <=1024) ----
__device__ inline void blk_reduce2(float& a, float& b, float* red) {
  #pragma unroll
  for (int off = 32; off > 0; off >>= 1) {
    a += __shfl_down(a, off, 64);
    b += __shfl_down(b, off, 64);
  }
  int w = threadIdx.x >> 6, lane = threadIdx.x & 63, nw = blockDim.x >> 6;
  __syncthreads();
  if (lane == 0) { red[w] = a; red[16 + w] = b; }
  __syncthreads();
  if (w == 0) {
    float sa = (lane < nw) ? red[lane] : 0.f;
    float sb = (lane < nw) ? red[16 + lane] : 0.f;
    #pragma unroll
    for (int off = 8; off > 0; off >>= 1) {
      sa += __shfl_down(sa, off, 64);
      sb += __shfl_down(sb, off, 64);
    }
    if (lane == 0) { red[32] = sa; red[33] = sb; }
  }
  __syncthreads();
  a = red[32]; b = red[33];
}

__device__ inline void blk_reduce1(float& a, float* red) {
  #pragma unroll
  for (int off = 32; off > 0; off >>= 1) a += __shfl_down(a, off, 64);
  int w = threadIdx.x >> 6, lane = threadIdx.x & 63, nw = blockDim.x >> 6;
  __syncthreads();
  if (lane == 0) red[w] = a;
  __syncthreads();
  if (w == 0) {
    float sa = (lane < nw) ? red[lane] : 0.f;
    #pragma unroll
    for (int off = 8; off > 0; off >>= 1) sa += __shfl_down(sa, off, 64);
    if (lane == 0) red[32] = sa;
  }
  __syncthreads();
  a = red[32];
}

// ---- K0: dtype flag detect + theta MLP + zero scalar & barrier slots ----
__global__ void k0_theta(const void* ste, const void* w1, const void* b1,
                         const void* w2, const void* b2, const void* gamma,
                         float* ws) {
  __shared__ int sflag;
  int tid = threadIdx.x;
  if (tid == 0) {
    unsigned bits = ((const unsigned*)gamma)[0];   // bn_gamma[0] == 1.0
    int f = (bits == 0x3F800000u) ? 0 : 1;
    sflag = f;
    ((int*)ws)[OF_FLAG] = f;
  }
  __syncthreads();
  int bf = sflag;
  if (tid < 264) {
    int b = tid / 66, r = tid % 66, o = r / 11, p = r % 11;
    float acc = ld_in(b2, p, bf);
    for (int s = 0; s < 10; ++s) {
      float h1 = ld_in(b1, o, bf);
      for (int t = 0; t < 5; ++t)
        h1 += ld_in(w1, o * 5 + t, bf) * ld_in(ste, (long)(b * 5 + t) * 10 + s, bf);
      acc += ld_in(w2, p * 10 + s, bf) * h1;
    }
    ws[OF_THETA + b * 66 + r] = fmaxf(acc, 0.f);
  }
  for (int q = tid; q < 2048; q += blockDim.x) ws[OF_SCAL + q] = 0.f;
  int* bi = (int*)(ws + OF_BAR);
  for (int q = tid; q < 704; q += blockDim.x) bi[q] = 0;
}

// ---- split sp into bf16 hi + residual-lo arrays, FRAGMENT-MAJOR layout:
//      elem (ng2,kc,quad,col,e) = sp[n=ng2*16+col][m=kc*32+quad*8+e]
//      -> a wave's B-frag load (lane=quad*16+col, 8 ushorts) is 1KB contiguous.
__global__ void k_conv(const void* sp, float* ws) {
  int bf = ((const int*)ws)[0];
  int i = blockIdx.x * 1024 + threadIdx.x;   // 0..262143
  int e = i & 7, c = (i >> 3) & 15, qd = (i >> 7) & 3, kc = (i >> 9) & 15, ng2 = i >> 13;
  long src = (long)(ng2 * 16 + c) * 512 + kc * 32 + qd * 8 + e;
  unsigned wv = packw(ld_in(sp, src, bf));
  ((unsigned short*)(ws + OF_SPH))[i] = (unsigned short)(wv & 0xFFFFu);
  ((unsigned short*)(ws + OF_SPL))[i] = (unsigned short)(wv >> 16);
}

// ---- per-slice nsq[0] = ||x||^2 (reads input directly) ----
__global__ __launch_bounds__(1024) void k_nrm0(const void* x, float* ws) {
  __shared__ float red[34];
  int slice = blockIdx.x, tid = threadIdx.x;
  int bf = ((const int*)ws)[0];
  long soff = (long)slice * 32768;
  float s = 0.f;
  #pragma unroll
  for (int k = 0; k < 32; ++k) { float v = ld_in(x, soff + k * 1024 + tid, bf); s += v * v; }
  blk_reduce1(s, red);
  if (tid == 0) ws[OF_SCAL + slice] = s;
}

// ---- v~_0 = x, stored TRANSPOSED [t][n] (unnormalized) ----
__global__ __launch_bounds__(256) void k_scaleT(const void* x, float* ws) {
  __shared__ float tile[64 * 65];
  int bid = blockIdx.x, tid = threadIdx.x;
  int slice = bid >> 3, nb = bid & 7;
  int bf = ((const int*)ws)[0];
  long soff = (long)slice * 32768;
  for (int q = 0; q < 16; ++q) {
    int idx = q * 256 + tid;
    int nl = idx >> 6, t = idx & 63;
    tile[nl * 65 + t] = ld_in(x, soff + (long)(nb * 64 + nl) * 64 + t, bf);
  }
  __syncthreads();
  float* mi = ws + OF_MI0 + soff;
  for (int q = 0; q < 16; ++q) {
    int idx = q * 256 + tid;
    int t = idx >> 6, nl = idx & 63;
    mi[t * 512 + nb * 64 + nl] = tile[nl * 65 + t];
  }
}

// ---- CK1: the ENTIRE s-chain (old k1m i=1..10 + k1z) in one persistent
//      launch. 256 blocks (slice,tb), 1 block/CU (LDS 97KB). Cross-block
//      traffic = per-slice scalars only, synced by a 4-block spin barrier
//      (release/acquire agent-scope atomics; all blocks co-resident).
//      r' lives in LDS (never global); v~_{i-2}/v~_{i-3} in registers;
//      epilogue dots read fp32 v~ from double-buffered RBv LDS.
//      A-operand staged as SEPARATE Wh/Wl bf16 arrays -> ds_read_b128,
//      no per-kc unpack VALU. B-frags: coalesced 1KB loads (fragment-major sp).
__global__ __launch_bounds__(1024, 4) void ck1(float* ws) {
  __shared__ float RBv[2][16 * 516];                 // fp32 v~ / r' ping-pong
  __shared__ __align__(16) unsigned short Wh[16 * 520];
  __shared__ __align__(16) unsigned short Wl[16 * 520];
  __shared__ float red[44];
  int tid = threadIdx.x, bid = blockIdx.x;
  // same-XCD grouping for the 4 blocks of a slice (assuming %8 round-robin;
  // wrong assumption only costs latency, not correctness)
  int slice = (bid & 7) * 8 + (bid >> 5);
  int tb = (bid >> 3) & 3;
  long soff = (long)slice * 32768;
  int w = tid >> 6, lane = tid & 63, quad = lane >> 4, col = lane & 15;
  int n0 = w * 32 + col, n1 = n0 + 16;
  int tlA = tid >> 7, m4 = tid & 127;
  const unsigned short* sph = (const unsigned short*)(ws + OF_SPH);
  const unsigned short* spl = (const unsigned short*)(ws + OF_SPL);
  int* bar = (int*)(ws + OF_BAR);

  float4 pv[2], pv2[2];
  pv[0] = float4{0.f, 0.f, 0.f, 0.f};  pv[1] = pv[0];
  pv2[0] = pv[0];                      pv2[1] = pv[0];

  for (int i = 1; i <= 11; ++i) {
    int cur = i & 1;
    float alpha = 0.f, beta = 0.f;
    if (i >= 2) {
      if (tid == 0) {
        int* slot = bar + (i - 2) * 64 + slice;
        __hip_atomic_fetch_add(slot, 1, __ATOMIC_RELEASE, __HIP_MEMORY_SCOPE_AGENT);
        while (__hip_atomic_load(slot, __ATOMIC_ACQUIRE, __HIP_MEMORY_SCOPE_AGENT) < 4)
          __builtin_amdgcn_s_sleep(1);
        float nq = __hip_atomic_load(&ws[OF_SCAL + (i - 2) * 64 + slice],
                                     __ATOMIC_RELAXED, __HIP_MEMORY_SCOPE_AGENT);
        float dA = __hip_atomic_load(&ws[OF_SCAL + 704 + (i - 2) * 64 + slice],
                                     __ATOMIC_RELAXED, __HIP_MEMORY_SCOPE_AGENT);
        red[40] = dA / fmaxf(nq, 1e-30f);
        float bb = 0.f;
        if (i >= 3) {
          float nq3 = __hip_atomic_load(&ws[OF_SCAL + (i - 3) * 64 + slice],
                                        __ATOMIC_RELAXED, __HIP_MEMORY_SCOPE_AGENT);
          float dB = __hip_atomic_load(&ws[OF_SCAL + 1344 + (i - 3) * 64 + slice],
                                       __ATOMIC_RELAXED, __HIP_MEMORY_SCOPE_AGENT);
          bb = dB / fmaxf(nq3, 1e-30f);
        }
        red[41] = bb;
      }
      __syncthreads();   // also orders prev epilogue LDS writes vs Phase A reads
      alpha = red[40]; beta = red[41];
    }

    // ---- Phase A: v~_{i-1} from r'(LDS) and reg history; stage fp32+bf16 ----
    float npp = 0.f;
    #pragma unroll
    for (int q = 0; q < 2; ++q) {
      int tl = tlA + q * 8;
      int lo = tl * 516 + m4 * 4;
      float4 v;
      if (i == 1) {
        v = *(const float4*)(ws + OF_MI0 + soff + (long)(tb * 16 + tl) * 512 + m4 * 4);
      } else {
        float4 r = *(const float4*)&RBv[cur][lo];
        v.x = r.x - alpha * pv[q].x - beta * pv2[q].x;
        v.y = r.y - alpha * pv[q].y - beta * pv2[q].y;
        v.z = r.z - alpha * pv[q].z - beta * pv2[q].z;
        v.w = r.w - alpha * pv[q].w - beta * pv2[q].w;
        *(float4*)(ws + OF_MI0 + (long)(i - 1) * 2097152 + soff
                   + (long)(tb * 16 + tl) * 512 + m4 * 4) = v;
        npp += v.x * v.x + v.y * v.y + v.z * v.z + v.w * v.w;
      }
      *(float4*)&RBv[cur][lo] = v;      // in-place over r' (same thread, same addr)
      pv2[q] = pv[q]; pv[q] = v;
      if (i <= 10) {
        unsigned p0 = packw(v.x), p1 = packw(v.y), p2 = packw(v.z), p3 = packw(v.w);
        u16x4 hv = { (unsigned short)(p0 & 0xFFFFu), (unsigned short)(p1 & 0xFFFFu),
                     (unsigned short)(p2 & 0xFFFFu), (unsigned short)(p3 & 0xFFFFu) };
        u16x4 lv = { (unsigned short)(p0 >> 16), (unsigned short)(p1 >> 16),
                     (unsigned short)(p2 >> 16), (unsigned short)(p3 >> 16) };
        *(u16x4*)&Wh[tl * 520 + m4 * 4] = hv;
        *(u16x4*)&Wl[tl * 520 + m4 * 4] = lv;
      }
    }
    if (i >= 2) {
      blk_reduce1(npp, red);
      if (tid == 0) atomicAdd(ws + OF_SCAL + (i - 1) * 64 + slice, npp);
    } else {
      __syncthreads();
    }
    if (i == 11) break;   // final step = materialize v~_10 + nsq[10] only

    // ---- Phase B: r'_{i-1} = v~ @ sp^T (3-product bf16 split) ----
    f32x4 C0 = {0.f, 0.f, 0.f, 0.f}, C1 = {0.f, 0.f, 0.f, 0.f};
    #pragma unroll 4
    for (int kc = 0; kc < 16; ++kc) {
      short8 ah = *(const short8*)&Wh[col * 520 + kc * 32 + quad * 8];
      short8 al = *(const short8*)&Wl[col * 520 + kc * 32 + quad * 8];
      long ob0 = (((long)(w * 2) * 16 + kc) * 64 + quad * 16 + col) * 8;
      long ob1 = (((long)(w * 2 + 1) * 16 + kc) * 64 + quad * 16 + col) * 8;
      short8 bh0 = *(const short8*)(sph + ob0);
      short8 bl0 = *(const short8*)(spl + ob0);
      short8 bh1 = *(const short8*)(sph + ob1);
      short8 bl1 = *(const short8*)(spl + ob1);
      C0 = __builtin_amdgcn_mfma_f32_16x16x32_bf16(ah, bh0, C0, 0, 0, 0);
      C0 = __builtin_amdgcn_mfma_f32_16x16x32_bf16(ah, bl0, C0, 0, 0, 0);
      C0 = __builtin_amdgcn_mfma_f32_16x16x32_bf16(al, bh0, C0, 0, 0, 0);
      C1 = __builtin_amdgcn_mfma_f32_16x16x32_bf16(ah, bh1, C1, 0, 0, 0);
      C1 = __builtin_amdgcn_mfma_f32_16x16x32_bf16(ah, bl1, C1, 0, 0, 0);
      C1 = __builtin_amdgcn_mfma_f32_16x16x32_bf16(al, bh1, C1, 0, 0, 0);
    }

    // ---- Epilogue: dots from fp32 LDS, r' -> other RBv buffer ----
    float d1p = 0.f, d2p = 0.f;
    #pragma unroll
    for (int r = 0; r < 4; ++r) {
      int tl = quad * 4 + r;
      float lv0 = RBv[cur][tl * 516 + n0];
      float lv1 = RBv[cur][tl * 516 + n1];
      d1p += C0[r] * lv0 + C1[r] * lv1;
      if (i >= 2)
        d2p += C0[r] * RBv[cur ^ 1][tl * 516 + n0] + C1[r] * RBv[cur ^ 1][tl * 516 + n1];
      RBv[cur ^ 1][tl * 516 + n0] = C0[r];   // read-then-write, thread-owned addrs
      RBv[cur ^ 1][tl * 516 + n1] = C1[r];
    }
    blk_reduce2(d1p, d2p, red);
    if (tid == 0) {
      atomicAdd(ws + OF_SCAL + 704 + (i - 1) * 64 + slice, d1p);
      if (i >= 2) atomicAdd(ws + OF_SCAL + 1344 + (i - 2) * 64 + slice, d2p);
    }
  }
}

// ---- K2m: bf16 MFMA t-chains (round-1 version, known-good @113us) ----
__global__ __launch_bounds__(1024, 4) void k2m(float* ws, const void* tp) {
  __shared__ unsigned LW[2][16384];
  __shared__ unsigned AH[2048];
  __shared__ float red[24];          // [j=1..5][d1,d2,nrm,pad]
  int tid = threadIdx.x;
  int slice = blockIdx.x / 11, ic = blockIdx.x % 11;
  int b = slice >> 4;
  int w = tid >> 6, lane = tid & 63, quad = lane >> 4, col = lane & 15;
  int mt = w & 3, ng = w >> 2;
  int bf = ((const int*)ws)[0];

  #pragma unroll
  for (int s = 0; s < 2; ++s) {
    int widx = s * 1024 + tid;
    int tq_ = widx & 3, ln = (widx >> 2) & 63, ktm = widx >> 8;
    int kt_ = ktm & 1, mt_ = ktm >> 1;
    int qd = ln >> 4, cl = ln & 15;
    int ua = mt_ * 16 + cl;
    int t0 = kt_ * 32 + qd * 8 + tq_ * 2;
    AH[widx] = pk2(ld_in(tp, (long)t0 * 64 + ua, bf),
                   ld_in(tp, (long)(t0 + 1) * 64 + ua, bf));
  }
  if (tid < 24) red[tid] = 0.f;

  float rinv = 1.f / fmaxf(sqrtf(ws[OF_SCAL + ic * 64 + slice]), EPS);
  float* seed = ws + OF_MI0 + (long)ic * 2097152 + (long)slice * 32768;

  for (int q = 0; q < 16; ++q) {
    int widx = q * 1024 + tid;
    int tpair = widx >> 9, n = widx & 511;
    float v0 = seed[(2 * tpair) * 512 + n] * rinv;
    float v1 = seed[(2 * tpair + 1) * 512 + n] * rinv;
    int li = ((tpair >> 2) * 512 + n) * 4 + (tpair & 3);
    LW[0][li] = pk2(v0, v1);
    LW[1][widx] = 0u;
  }
  __syncthreads();

  int t8c = mt * 2 + (quad >> 1);
  int tq0 = (quad * 2) & 3;
  float c0 = ws[OF_THETA + b * 66 + ic * 6 + 0];

  unsigned accP[16];
  #pragma unroll
  for (int nti = 0; nti < 8; ++nti) {
    int nn = ng * 128 + nti * 16 + col;
    int base = (t8c * 512 + nn) * 4;
    uint2 lw = *(uint2*)&LW[0][base + tq0];
    float2 p01 = upk2(lw.x), p23 = upk2(lw.y);
    accP[nti * 2] = pk2(c0 * p01.x, c0 * p01.y);
    accP[nti * 2 + 1] = pk2(c0 * p23.x, c0 * p23.y);
  }

  unsigned* cur = &LW[0][0];
  unsigned* prv = &LW[1][0];

  for (int j = 1; j <= 5; ++j) {
    f32x4 C[8];
    #pragma unroll
    for (int nti = 0; nti < 8; ++nti) C[nti] = (f32x4){0.f, 0.f, 0.f, 0.f};
    #pragma unroll
    for (int kt = 0; kt < 2; ++kt) {
      short8 a = *(short8*)&AH[((mt * 2 + kt) * 64 + lane) * 4];
      #pragma unroll
      for (int nti = 0; nti < 8; ++nti) {
        int bn = ng * 128 + nti * 16 + col;
        short8 bb = *(short8*)&cur[((kt * 4 + quad) * 512 + bn) * 4];
        C[nti] = __builtin_amdgcn_mfma_f32_16x16x32_bf16(a, bb, C[nti], 0, 0, 0);
      }
    }
    uint2 rlc[8], rlp[8];
    float d1p = 0.f, d2p = 0.f, nrm = 0.f;
    #pragma unroll
    for (int nti = 0; nti < 8; ++nti) {
      int nn = ng * 128 + nti * 16 + col;
      int base = (t8c * 512 + nn) * 4;
      rlc[nti] = *(uint2*)&cur[base + tq0];
      rlp[nti] = *(uint2*)&prv[base + tq0];
      float2 l01 = upk2(rlc[nti].x), l23 = upk2(rlc[nti].y);
      float2 s01 = upk2(rlp[nti].x), s23 = upk2(rlp[nti].y);
      d1p += C[nti][0] * l01.x + C[nti][1] * l01.y + C[nti][2] * l23.x + C[nti][3] * l23.y;
      d2p += C[nti][0] * s01.x + C[nti][1] * s01.y + C[nti][2] * s23.x + C[nti][3] * s23.y;
      nrm += C[nti][0] * C[nti][0] + C[nti][1] * C[nti][1]
           + C[nti][2] * C[nti][2] + C[nti][3] * C[nti][3];
    }
    #pragma unroll
    for (int off = 32; off > 0; off >>= 1) {
      d1p += __shfl_down(d1p, off, 64);
      d2p += __shfl_down(d2p, off, 64);
      nrm += __shfl_down(nrm, off, 64);
    }
    if (lane == 0) {
      atomicAdd(&red[j * 4 + 0], d1p);
      atomicAdd(&red[j * 4 + 1], d2p);
      atomicAdd(&red[j * 4 + 2], nrm);
    }
    __syncthreads();
    float d1 = red[j * 4 + 0], d2 = red[j * 4 + 1], nr = red[j * 4 + 2];
    float np = fmaxf(nr - d1 * d1 - d2 * d2, 0.f);
    float ri = 1.f / fmaxf(sqrtf(np), EPS);
    float cj = ws[OF_THETA + b * 66 + ic * 6 + j];
    #pragma unroll
    for (int nti = 0; nti < 8; ++nti) {
      int nn = ng * 128 + nti * 16 + col;
      int base = (t8c * 512 + nn) * 4;
      float2 l01 = upk2(rlc[nti].x), l23 = upk2(rlc[nti].y);
      float2 s01 = upk2(rlp[nti].x), s23 = upk2(rlp[nti].y);
      float vh0 = (C[nti][0] - d1 * l01.x - d2 * s01.x) * ri;
      float vh1 = (C[nti][1] - d1 * l01.y - d2 * s01.y) * ri;
      float vh2 = (C[nti][2] - d1 * l23.x - d2 * s23.x) * ri;
      float vh3 = (C[nti][3] - d1 * l23.y - d2 * s23.y) * ri;
      float2 a0 = upk2(accP[nti * 2]), a1 = upk2(accP[nti * 2 + 1]);
      accP[nti * 2] = pk2(a0.x + cj * vh0, a0.y + cj * vh1);
      accP[nti * 2 + 1] = pk2(a1.x + cj * vh2, a1.y + cj * vh3);
      uint2 nw; nw.x = pk2(vh0, vh1); nw.y = pk2(vh2, vh3);
      *(uint2*)&prv[base + tq0] = nw;
    }
    unsigned* t = cur; cur = prv; prv = t;
    __syncthreads();
  }
  float* po = seed;   // block-owned consumed seed region -> plain stores
  #pragma unroll
  for (int nti = 0; nti < 8; ++nti) {
    int nn = ng * 128 + nti * 16 + col;
    int u0 = mt * 16 + quad * 4;
    float2 a0 = upk2(accP[nti * 2]), a1 = upk2(accP[nti * 2 + 1]);
    po[(u0 + 0) * 512 + nn] = a0.x;
    po[(u0 + 1) * 512 + nn] = a0.y;
    po[(u0 + 2) * 512 + nn] = a1.x;
    po[(u0 + 3) * 512 + nn] = a1.y;
  }
}

// ---- K2r: XST = sum over ic of the 11 chain partials (streaming, no atomics) ----
__global__ __launch_bounds__(256) void k2r(float* ws) {
  long i = ((long)blockIdx.x * 256 + threadIdx.x) * 4;
  float4 s = *(const float4*)(ws + OF_MI0 + i);
  #pragma unroll
  for (int ic = 1; ic <= 10; ++ic) {
    float4 v = *(const float4*)(ws + OF_MI0 + (long)ic * 2097152 + i);
    s.x += v.x; s.y += v.y; s.z += v.z; s.w += v.w;
  }
  *(float4*)(ws + OF_XST + i) = s;
}

// ---- K3: out = BN(MLP([x, x_st])); xst is [c][t][n] -> LDS tile transpose ----
__global__ __launch_bounds__(1024) void k3(const void* x, const void* wmlp, const void* bmlp,
    const void* gam, const void* bet, const void* mea, const void* var,
    const float* ws, void* out) {
  __shared__ float wA[64 * 16], wB[64 * 16], winv[64], wsh[64], wb[64];
  __shared__ float tile[16 * 64 * 17];   // [f][t][16n + pad]
  int tid = threadIdx.x, bid = blockIdx.x;
  int bf = ((const int*)ws)[0];
  int b = bid >> 5, nbase = (bid & 31) * 16;
  if (tid < 64) {
    float g = ld_in(gam, tid, bf), vv = ld_in(var, tid, bf);
    float iv = g / sqrtf(vv + 1e-5f);
    winv[tid] = iv;
    wsh[tid] = ld_in(bet, tid, bf) - ld_in(mea, tid, bf) * iv;
    wb[tid] = ld_in(bmlp, tid, bf);
  }
  for (int q = tid; q < 2048; q += 1024) {
    int o = q >> 5, c = q & 31;
    float v = ld_in(wmlp, q, bf);
    if (c < 16) wA[o * 16 + c] = v; else wB[o * 16 + (c - 16)] = v;
  }
  const float* xst = ws + OF_XST;
  #pragma unroll
  for (int q = 0; q < 4; ++q) {
    int idx = q * 1024 + tid;
    int f = idx >> 8, t = (idx >> 2) & 63, dn4 = idx & 3;
    float4 v = *(const float4*)(xst + ((long)(b * 16 + f)) * 32768 + t * 512 + nbase + dn4 * 4);
    float* dst = tile + f * 1088 + t * 17 + dn4 * 4;
    dst[0] = v.x; dst[1] = v.y; dst[2] = v.z; dst[3] = v.w;
  }
  __syncthreads();
  long pos = (long)(bid & 31) * 1024 + tid;
  int t = tid & 63, nl = tid >> 6;
  float xv[16], av[16];
  #pragma unroll
  for (int c = 0; c < 16; ++c)
    xv[c] = ld_in(x, ((long)(b * 16 + c)) * 32768 + pos, bf);
  #pragma unroll
  for (int f = 0; f < 16; ++f)
    av[f] = tile[f * 1088 + t * 17 + nl];
  #pragma unroll 4
  for (int o = 0; o < 64; ++o) {
    float s = wb[o];
    #pragma unroll
    for (int c = 0; c < 16; ++c) s += wA[o * 16 + c] * xv[c];
    #pragma unroll
    for (int f = 0; f < 16; ++f) s += wB[o * 16 + f] * av[f];
    s = s * winv[o] + wsh[o];
    long oi = ((long)(b * 64 + o)) * 32768 + pos;
    if (bf) ((__hip_bfloat16*)out)[oi] = __float2bfloat16(s);
    else ((float*)out)[oi] = s;
  }
}

extern "C" void kernel_launch(void* const* d_in, const int* in_sizes, int n_in,
                              void* d_out, int out_size, void* d_ws, size_t ws_size,
                              hipStream_t stream) {
  (void)in_sizes; (void)n_in; (void)out_size; (void)ws_size;
  float* ws = (float*)d_ws;

  k0_theta<<<1, 320, 0, stream>>>(d_in[3], d_in[4], d_in[5], d_in[6], d_in[7], d_in[10], ws);
  k_conv<<<256, 1024, 0, stream>>>(d_in[1], ws);
  k_nrm0<<<64, 1024, 0, stream>>>(d_in[0], ws);
  k_scaleT<<<512, 256, 0, stream>>>(d_in[0], ws);
  ck1<<<256, 1024, 0, stream>>>(ws);
  k2m<<<704, 1024, 0, stream>>>(ws, d_in[2]);
  k2r<<<2048, 256, 0, stream>>>(ws);
  k3<<<128, 1024, 0, stream>>>(d_in[0], d_in[8], d_in[9], d_in[10], d_in[11], d_in[12], d_in[13],
                               ws, d_out);
}